// Round 10
// baseline (233.825 us; speedup 1.0000x reference)
//
#include <hip/hip_runtime.h>
#include <hip/hip_bf16.h>
#include <cstdint>

#define B_ 8
#define C_ 512
#define T_ 1500
#define N_ (B_*T_)      // 12000 tokens
#define NPAD_ 12032
#define V_ 4096
#define K_ 100

typedef unsigned long long u64;
typedef __attribute__((ext_vector_type(8))) short short8;
typedef __attribute__((ext_vector_type(8))) unsigned short u16x8;
typedef __attribute__((ext_vector_type(4))) float f32x4;

__device__ __forceinline__ unsigned short f2bf(float x){
    __hip_bfloat16 h = __float2bfloat16(x);
    return __builtin_bit_cast(unsigned short, h);
}
__device__ __forceinline__ unsigned short f2h(float x){
    return __builtin_bit_cast(unsigned short, (_Float16)x);
}
__device__ __forceinline__ float h2f(unsigned short h){
    return (float)__builtin_bit_cast(_Float16, h);
}

__device__ __forceinline__ void gll16(const unsigned short* g, unsigned short* l){
    __builtin_amdgcn_global_load_lds(
        (const __attribute__((address_space(1))) void*)g,
        (__attribute__((address_space(3))) void*)l, 16, 0, 0);
}

// ---------------- codebook: fp32 -> bf16 + csq (fp32-exact) ----------------
__global__ __launch_bounds__(256) void cbconv_kernel(const float* __restrict__ CB,
                                                     unsigned short* __restrict__ CBh,
                                                     float* __restrict__ csq){
    int wv = threadIdx.x >> 6, lane = threadIdx.x & 63;
    int r = blockIdx.x * 4 + wv;
    const float4* p4 = (const float4*)(CB + (size_t)r * C_);
    ushort4* o4 = (ushort4*)(CBh + (size_t)r * C_);
    float s = 0.f;
    #pragma unroll
    for (int j = 0; j < 2; ++j){
        float4 v = p4[lane + j*64];
        s += v.x*v.x + v.y*v.y + v.z*v.z + v.w*v.w;
        ushort4 h; h.x = f2bf(v.x); h.y = f2bf(v.y); h.z = f2bf(v.z); h.w = f2bf(v.w);
        o4[lane + j*64] = h;
    }
    #pragma unroll
    for (int o = 32; o; o >>= 1) s += __shfl_down(s, o, 64);
    if (lane == 0) csq[r] = s;
}

// ---------------- student: (B,C,T) fp32 -> embT bf16 (N,C) + esq partials ----------------
__global__ __launch_bounds__(256) void transpose_conv_kernel(const float* __restrict__ S,
                                                             unsigned short* __restrict__ embT,
                                                             float* __restrict__ esq){
    __shared__ float tile[32][33];
    __shared__ float psum[8][33];
    int b  = blockIdx.z;
    int c0 = blockIdx.y * 32;
    int t0 = blockIdx.x * 32;
    int tx = threadIdx.x, ty = threadIdx.y; // 32 x 8
    #pragma unroll
    for (int r = 0; r < 4; ++r){
        int c = c0 + ty + r*8;
        int t = t0 + tx;
        tile[ty + r*8][tx] = (t < T_) ? S[((size_t)b*C_ + c)*T_ + t] : 0.f;
    }
    __syncthreads();
    float ps = 0.f;
    #pragma unroll
    for (int r = 0; r < 4; ++r){ float v = tile[ty + r*8][tx]; ps += v * v; }
    psum[ty][tx] = ps;
    #pragma unroll
    for (int r = 0; r < 4; ++r){
        int t = t0 + ty + r*8;
        int c = c0 + tx;
        if (t < T_) embT[((size_t)b*T_ + t)*C_ + c] = f2bf(tile[tx][ty + r*8]);
    }
    __syncthreads();
    if (ty == 0){
        int t = t0 + tx;
        if (t < T_){
            float s2 = 0.f;
            #pragma unroll
            for (int w = 0; w < 8; ++w) s2 += psum[w][tx];
            atomicAdd(&esq[b*T_ + t], s2);
        }
    }
}

// ---------------- bf16 MFMA GEMM -> fp16 dot matrix (r2-proven 2-barrier 128^2) ----------------
__global__ __launch_bounds__(256) void gemm_dot_kernel(
    const unsigned short* __restrict__ A, const unsigned short* __restrict__ Bm,
    unsigned short* __restrict__ doth, int row_lo, int row_hi)
{
    __shared__ unsigned short smem[128*136];   // 34816 B; staging (16 KB) aliased in front
    unsigned short* As = smem;                 // 128*32
    unsigned short* Bs = smem + 128*32;        // 128*32
    int tid = threadIdx.x, lane = tid & 63, wv = tid >> 6;
    int row0 = row_lo + blockIdx.x * 128;
    int col0 = blockIdx.y * 128;

    int sr = lane >> 2;
    int sk = (lane & 3) * 8;
    int ar0 = row0 + wv*32 + sr;       int ar1 = ar0 + 16;
    int ca0 = (ar0 < N_) ? ar0 : N_-1; int ca1 = (ar1 < N_) ? ar1 : N_-1;
    const unsigned short* Ap0 = A  + (size_t)ca0 * C_ + sk;
    const unsigned short* Ap1 = A  + (size_t)ca1 * C_ + sk;
    const unsigned short* Bp0 = Bm + (size_t)(col0 + wv*32 + sr) * C_ + sk;
    const unsigned short* Bp1 = Bp0 + (size_t)16 * C_;
    unsigned short* Ad0 = &As[(wv*32     ) * 32];
    unsigned short* Ad1 = &As[(wv*32 + 16) * 32];
    unsigned short* Bd0 = &Bs[(wv*32     ) * 32];
    unsigned short* Bd1 = &Bs[(wv*32 + 16) * 32];

    int wm = (wv >> 1) * 64, wn = (wv & 1) * 64;
    int fr = lane & 15;
    int fk = (lane >> 4) * 8;

    f32x4 acc[4][4];
    #pragma unroll
    for (int i = 0; i < 4; ++i)
        #pragma unroll
        for (int j = 0; j < 4; ++j) acc[i][j] = (f32x4){0.f, 0.f, 0.f, 0.f};

    for (int kt = 0; kt < C_/32; ++kt){
        int k0 = kt * 32;
        gll16(Ap0 + k0, Ad0);
        gll16(Ap1 + k0, Ad1);
        gll16(Bp0 + k0, Bd0);
        gll16(Bp1 + k0, Bd1);
        __syncthreads();
        short8 af[4], bf[4];
        #pragma unroll
        for (int i = 0; i < 4; ++i) af[i] = *(const short8*)&As[(wm + i*16 + fr)*32 + fk];
        #pragma unroll
        for (int j = 0; j < 4; ++j) bf[j] = *(const short8*)&Bs[(wn + j*16 + fr)*32 + fk];
        #pragma unroll
        for (int i = 0; i < 4; ++i)
            #pragma unroll
            for (int j = 0; j < 4; ++j)
                acc[i][j] = __builtin_amdgcn_mfma_f32_16x16x32_bf16(bf[j], af[i], acc[i][j], 0, 0, 0);
        __syncthreads();
    }
    // loop ends with a barrier: safe to alias smem for the out-tile.

    // ---- stage 1: pack fp16 into LDS out-tile [128][136] ----
    const int LD = 136;
    int en = lane & 15;
    int ev = (lane >> 4) * 4;
    #pragma unroll
    for (int i = 0; i < 4; ++i){
        int r = wm + i*16 + en;
        #pragma unroll
        for (int j = 0; j < 4; ++j){
            ushort4 h;
            h.x = f2h(acc[i][j][0]);
            h.y = f2h(acc[i][j][1]);
            h.z = f2h(acc[i][j][2]);
            h.w = f2h(acc[i][j][3]);
            *(ushort4*)&smem[r*LD + wn + j*16 + ev] = h;
        }
    }
    __syncthreads();

    // ---- stage 2: coalesced stores, 16 lanes cover one row's 256B ----
    int rr = tid >> 4;          // 0..15
    int cc = (tid & 15) * 8;    // element col, 16B per lane
    #pragma unroll
    for (int it = 0; it < 8; ++it){
        int r = it*16 + rr;
        int n = row0 + r;
        if (n < row_hi){
            u16x8 v = *(const u16x8*)&smem[r*LD + cc];
            *(u16x8*)&doth[(size_t)(n - row_lo) * V_ + col0 + cc] = v;
        }
    }
}

// ---------------- selection v4.2: 1 wave/block (occupancy) + split serial chains ----------------
// Same algorithm as r9's v4.1 (proven 64 us). Deltas:
//  - 64-thread blocks (wave-independent code, no barriers): CU can pack waves to the
//    VGPR limit instead of 4-wave-block granularity; smoother tail.
//  - min/max tracked in two independent half-chains (k<32 | k>=32); merge keeps the
//    lowest-global-idx tie rule (idx strictly increases with j, so half A wins ties).
//  - softmax accumulated in 4 independent chains, merged at the end.
__global__ __launch_bounds__(64, 4) void select_kernel(const unsigned short* __restrict__ doth,
                                                       const int* __restrict__ codes,
                                                       const float* __restrict__ esq,
                                                       const float* __restrict__ csq,
                                                       float2* __restrict__ pairbuf,
                                                       int row_lo, int nrows){
    int lane = threadIdx.x;
    int lrow = blockIdx.x;
    if (lrow >= nrows) return;
    int n = row_lo + lrow;
    const u16x8* r8 = (const u16x8*)(doth + (size_t)lrow * V_);

    __shared__ unsigned hist[256] __attribute__((aligned(16)));
    __shared__ unsigned coll[64];
    __shared__ unsigned collcnt;

    float esq_n = esq[n];
    int code = codes[n];
    float dotc = h2f(doth[(size_t)lrow * V_ + code]);
    unsigned ucode = __float_as_uint(fmaxf(esq_n + csq[code] - 2.f * dotc, 0.f));

    // ---- load + reconstruct d2 bits, fused min/argmin/max in two half-chains ----
    unsigned u[64];
    unsigned mnA = 0xFFFFFFFFu, mxA = 0u, mnB = 0xFFFFFFFFu, mxB = 0u;
    int kmA = 0, kmB = 32;
    #pragma unroll
    for (int j = 0; j < 8; ++j){
        u16x8 h = r8[lane + j*64];
        const float4* cp = (const float4*)(csq + 8*lane + 512*j);
        float4 c0 = cp[0], c1 = cp[1];
        float cs[8] = {c0.x, c0.y, c0.z, c0.w, c1.x, c1.y, c1.z, c1.w};
        #pragma unroll
        for (int e = 0; e < 8; ++e){
            int k = 8*j + e;
            unsigned v = __float_as_uint(fmaxf(esq_n + cs[e] - 2.f * h2f(h[e]), 0.f));
            u[k] = v;
            if (j < 4){
                if (v < mnA){ mnA = v; kmA = k; }
                mxA = (v > mxA) ? v : mxA;
            } else {
                if (v < mnB){ mnB = v; kmB = k; }
                mxB = (v > mxB) ? v : mxB;
            }
        }
    }
    // merge halves: half A's global indices are all < half B's (idx grows with j),
    // so on equal values half A wins -> strict < for B.
    unsigned vmn = mnA; int km = kmA;
    if (mnB < mnA){ vmn = mnB; km = kmB; }
    unsigned vmx = (mxA > mxB) ? mxA : mxB;

    unsigned im = 8u*(unsigned)lane + (unsigned)(512*(km >> 3) + (km & 7));
    #pragma unroll
    for (int o = 32; o; o >>= 1){
        unsigned v2 = (unsigned)__shfl_xor((int)vmn, o, 64);
        unsigned i2 = (unsigned)__shfl_xor((int)im,  o, 64);
        if (v2 < vmn || (v2 == vmn && i2 < im)){ vmn = v2; im = i2; }
        unsigned x2 = (unsigned)__shfl_xor((int)vmx, o, 64); if (x2 > vmx) vmx = x2;
    }
    unsigned umin = vmn, umax = vmx;
    int idx0 = (int)im;
    float d0 = sqrtf(__uint_as_float(umin));

    // ---- rank-99 threshold t via histogram + in-bin bitwise search ----
    unsigned t;
    if (umin == umax){
        t = umin;
    } else {
        ((uint4*)&hist[0])[lane] = (uint4){0u,0u,0u,0u};
        if (lane == 0) collcnt = 0u;
        asm volatile("s_waitcnt lgkmcnt(0)" ::: "memory");
        float fmn = __uint_as_float(umin), fmx = __uint_as_float(umax);
        float invw = 256.0f / (fmx - fmn);
        #pragma unroll
        for (int k = 0; k < 64; ++k){
            float fk = __uint_as_float(u[k]);
            int b = (int)((fk - fmn) * invw); b = (b > 255) ? 255 : b;
            atomicAdd(&hist[b], 1u);
        }
        asm volatile("s_waitcnt lgkmcnt(0)" ::: "memory");
        uint4 hq = ((uint4*)&hist[0])[lane];
        unsigned lsum = hq.x + hq.y + hq.z + hq.w;
        unsigned inc = lsum;
        #pragma unroll
        for (int o = 1; o < 64; o <<= 1){
            unsigned y = (unsigned)__shfl_up((int)inc, o, 64);
            if (lane >= o) inc += y;
        }
        unsigned e0 = inc - lsum;
        unsigned e1 = e0 + hq.x, e2 = e1 + hq.y, e3 = e2 + hq.z, e4 = e3 + hq.w;
        int sel = -1;
        if      (e0 <= 99u && 99u < e1) sel = 0;
        else if (e1 <= 99u && 99u < e2) sel = 1;
        else if (e2 <= 99u && 99u < e3) sel = 2;
        else if (e3 <= 99u && 99u < e4) sel = 3;
        u64 bal = __ballot(sel >= 0);
        int src = __ffsll(bal) - 1;
        unsigned myBk = (unsigned)(4*lane + (sel < 0 ? 0 : sel));
        unsigned myBase = (sel == 1) ? e1 : (sel == 2) ? e2 : (sel == 3) ? e3 : e0;
        int Bk   = __shfl((int)myBk,   src, 64);
        int base = __shfl((int)myBase, src, 64);
        int rk = 99 - base;
        #pragma unroll
        for (int k = 0; k < 64; ++k){
            float fk = __uint_as_float(u[k]);
            int b = (int)((fk - fmn) * invw); b = (b > 255) ? 255 : b;
            if (b == Bk){
                unsigned pos = atomicAdd(&collcnt, 1u);
                if (pos < 64u) coll[pos] = u[k];
            }
        }
        asm volatile("s_waitcnt lgkmcnt(0)" ::: "memory");
        unsigned bcnt = collcnt;
        if (bcnt <= 64u){
            unsigned w = (lane < (int)bcnt) ? coll[lane] : 0xFFFFFFFFu;
            unsigned wmn = (lane < (int)bcnt) ? w : 0xFFFFFFFFu;
            unsigned wmx = (lane < (int)bcnt) ? w : 0u;
            #pragma unroll
            for (int o = 32; o; o >>= 1){
                unsigned a = (unsigned)__shfl_xor((int)wmn, o, 64); if (a < wmn) wmn = a;
                unsigned b = (unsigned)__shfl_xor((int)wmx, o, 64); if (b > wmx) wmx = b;
            }
            unsigned P;
            if (wmn == wmx) P = wmn;
            else {
                int hb = 31 - __clz((int)(wmn ^ wmx));
                unsigned mask = (hb == 31) ? 0xFFFFFFFFu : ((1u << (hb+1)) - 1u);
                P = wmn & ~mask;
                for (int b = hb; b >= 0; --b){
                    unsigned cand = P | (1u << b);
                    int c = __popcll(__ballot(w < cand));
                    if (c <= rk) P = cand;
                }
            }
            t = P;
        } else {
            int hb = 31 - __clz((int)(umin ^ umax));
            unsigned mask = (hb == 31) ? 0xFFFFFFFFu : ((1u << (hb+1)) - 1u);
            unsigned P = umin & ~mask;
            for (int b = hb; b >= 0; --b){
                unsigned cand = P | (1u << b);
                int c = 0;
                #pragma unroll
                for (int k = 0; k < 64; ++k) c += (u[k] < cand) ? 1 : 0;
                #pragma unroll
                for (int o = 32; o; o >>= 1) c += __shfl_xor(c, o, 64);
                if (c <= 99) P = cand;
            }
            t = P;
        }
    }
    float tval = sqrtf(__uint_as_float(t));

    // ---- softmax denom over top-100: 4 independent accumulation chains ----
    float s0 = 0.f, s1 = 0.f, s2 = 0.f, s3 = 0.f;
    int c0i = 0, c1i = 0, c2i = 0, c3i = 0;
    #pragma unroll
    for (int k = 0; k < 64; k += 4){
        if (u[k  ] < t){ s0 += __expf(d0 - sqrtf(__uint_as_float(u[k  ]))); c0i++; }
        if (u[k+1] < t){ s1 += __expf(d0 - sqrtf(__uint_as_float(u[k+1]))); c1i++; }
        if (u[k+2] < t){ s2 += __expf(d0 - sqrtf(__uint_as_float(u[k+2]))); c2i++; }
        if (u[k+3] < t){ s3 += __expf(d0 - sqrtf(__uint_as_float(u[k+3]))); c3i++; }
    }
    float s = (s0 + s1) + (s2 + s3);
    int cl = (c0i + c1i) + (c2i + c3i);
    #pragma unroll
    for (int o = 32; o; o >>= 1){
        s += __shfl_xor(s, o, 64);
        cl += __shfl_xor(cl, o, 64);
    }
    if (lane == 0){
        float S = s + (float)(K_ - cl) * __expf(d0 - tval);
        float dcode = sqrtf(__uint_as_float(ucode));
        if (ucode > t) S += __expf(d0 - dcode) - __expf(d0 - tval);  // include_correct swap
        float nll = dcode - d0 + __logf(S);
        pairbuf[n] = make_float2(nll, (idx0 == code) ? 1.f : 0.f);
    }
}

__global__ __launch_bounds__(1024) void finalize_kernel(const float2* __restrict__ pair,
                                                        float* __restrict__ out){
    int tid = threadIdx.x;
    float sn = 0.f, sh = 0.f;
    for (int i = tid; i < N_; i += 1024){
        float2 p = pair[i]; sn += p.x; sh += p.y;
    }
    #pragma unroll
    for (int o = 32; o; o >>= 1){ sn += __shfl_down(sn, o, 64); sh += __shfl_down(sh, o, 64); }
    __shared__ float a[16], b[16];
    int wv = tid >> 6, lane = tid & 63;
    if (lane == 0){ a[wv] = sn; b[wv] = sh; }
    __syncthreads();
    if (tid == 0){
        float L = 0.f, H = 0.f;
        #pragma unroll
        for (int i = 0; i < 16; ++i){ L += a[i]; H += b[i]; }
        out[0] = L / (float)N_;
        out[1] = H / (float)N_;   // local prediction is always candidate 0
        out[2] = H / (float)N_;
        out[3] = 1.0f;            // include_correct guarantees membership
    }
}

// ---------------- launcher (gemm split 2, single full-N select) ----------------
extern "C" void kernel_launch(void* const* d_in, const int* in_sizes, int n_in,
                              void* d_out, int out_size, void* d_ws, size_t ws_size,
                              hipStream_t stream){
    const float* S   = (const float*)d_in[0];
    const int* codes = (const int*)d_in[1];
    const float* CB  = (const float*)d_in[2];
    float* out = (float*)d_out;

    char* w = (char*)d_ws;
    size_t off = 0;
    unsigned short* embT = (unsigned short*)(w + off); off += (size_t)NPAD_ * C_ * 2;
    unsigned short* CBh  = (unsigned short*)(w + off); off += (size_t)V_ * C_ * 2;
    float* csq = (float*)(w + off); off += (size_t)V_ * 4;
    float* esq = (float*)(w + off); off += (size_t)N_ * 4;
    off = (off + 255) & ~(size_t)255;
    float2* pairbuf = (float2*)(w + off); off += (size_t)N_ * 8;
    unsigned short* dotbuf = (unsigned short*)(w + off);

    size_t avail = (ws_size > off) ? ws_size - off : 0;
    long maxrows = (long)(avail / ((size_t)V_ * 2));

    hipMemsetAsync(esq, 0, (size_t)N_ * 4, stream);
    hipLaunchKernelGGL(cbconv_kernel, dim3(V_/4), dim3(256), 0, stream, CB, CBh, csq);
    hipLaunchKernelGGL(transpose_conv_kernel, dim3((T_+31)/32, C_/32, B_), dim3(32, 8), 0, stream,
                       S, embT, esq);

    if (maxrows >= N_){
        const int gchunk = 6144;   // multiple of 128
        for (int row_lo = 0; row_lo < N_; row_lo += gchunk){
            int row_hi = row_lo + gchunk; if (row_hi > N_) row_hi = N_;
            int rows = row_hi - row_lo;
            hipLaunchKernelGGL(gemm_dot_kernel, dim3((rows + 127)/128, V_/128), dim3(256), 0, stream,
                               embT, CBh, dotbuf + (size_t)row_lo * V_, row_lo, row_hi);
        }
        hipLaunchKernelGGL(select_kernel, dim3(N_), dim3(64), 0, stream,
                           dotbuf, codes, esq, csq, pairbuf, 0, N_);
    } else {
        int chunk = (int)(maxrows & ~127L);
        if (chunk < 128) chunk = 128;
        for (int row_lo = 0; row_lo < N_; row_lo += chunk){
            int row_hi = row_lo + chunk; if (row_hi > N_) row_hi = N_;
            int rows = row_hi - row_lo;
            hipLaunchKernelGGL(gemm_dot_kernel, dim3((rows + 127)/128, V_/128), dim3(256), 0, stream,
                               embT, CBh, dotbuf, row_lo, row_hi);
            hipLaunchKernelGGL(select_kernel, dim3(rows), dim3(64), 0, stream,
                               dotbuf, codes, esq, csq, pairbuf, row_lo, rows);
        }
    }
    hipLaunchKernelGGL(finalize_kernel, dim3(1), dim3(1024), 0, stream, pairbuf, out);
}

// Round 11
// 216.909 us; speedup vs baseline: 1.0780x; 1.0780x over previous
//
#include <hip/hip_runtime.h>
#include <hip/hip_bf16.h>
#include <cstdint>

#define B_ 8
#define C_ 512
#define T_ 1500
#define N_ (B_*T_)      // 12000 tokens
#define NPAD_ 12032
#define V_ 4096
#define K_ 100

typedef unsigned long long u64;
typedef __attribute__((ext_vector_type(8))) short short8;
typedef __attribute__((ext_vector_type(8))) unsigned short u16x8;
typedef __attribute__((ext_vector_type(4))) float f32x4;

__device__ __forceinline__ unsigned short f2bf(float x){
    __hip_bfloat16 h = __float2bfloat16(x);
    return __builtin_bit_cast(unsigned short, h);
}
__device__ __forceinline__ unsigned short f2h(float x){
    return __builtin_bit_cast(unsigned short, (_Float16)x);
}
__device__ __forceinline__ float h2f(unsigned short h){
    return (float)__builtin_bit_cast(_Float16, h);
}

__device__ __forceinline__ void gll16(const unsigned short* g, unsigned short* l){
    __builtin_amdgcn_global_load_lds(
        (const __attribute__((address_space(1))) void*)g,
        (__attribute__((address_space(3))) void*)l, 16, 0, 0);
}

// ---------------- codebook: fp32 -> bf16 + csq (fp32-exact) ----------------
__global__ __launch_bounds__(256) void cbconv_kernel(const float* __restrict__ CB,
                                                     unsigned short* __restrict__ CBh,
                                                     float* __restrict__ csq){
    int wv = threadIdx.x >> 6, lane = threadIdx.x & 63;
    int r = blockIdx.x * 4 + wv;
    const float4* p4 = (const float4*)(CB + (size_t)r * C_);
    ushort4* o4 = (ushort4*)(CBh + (size_t)r * C_);
    float s = 0.f;
    #pragma unroll
    for (int j = 0; j < 2; ++j){
        float4 v = p4[lane + j*64];
        s += v.x*v.x + v.y*v.y + v.z*v.z + v.w*v.w;
        ushort4 h; h.x = f2bf(v.x); h.y = f2bf(v.y); h.z = f2bf(v.z); h.w = f2bf(v.w);
        o4[lane + j*64] = h;
    }
    #pragma unroll
    for (int o = 32; o; o >>= 1) s += __shfl_down(s, o, 64);
    if (lane == 0) csq[r] = s;
}

// ---------------- student: (B,C,T) fp32 -> embT bf16 (N,C) + esq partials ----------------
__global__ __launch_bounds__(256) void transpose_conv_kernel(const float* __restrict__ S,
                                                             unsigned short* __restrict__ embT,
                                                             float* __restrict__ esq){
    __shared__ float tile[32][33];
    __shared__ float psum[8][33];
    int b  = blockIdx.z;
    int c0 = blockIdx.y * 32;
    int t0 = blockIdx.x * 32;
    int tx = threadIdx.x, ty = threadIdx.y; // 32 x 8
    #pragma unroll
    for (int r = 0; r < 4; ++r){
        int c = c0 + ty + r*8;
        int t = t0 + tx;
        tile[ty + r*8][tx] = (t < T_) ? S[((size_t)b*C_ + c)*T_ + t] : 0.f;
    }
    __syncthreads();
    float ps = 0.f;
    #pragma unroll
    for (int r = 0; r < 4; ++r){ float v = tile[ty + r*8][tx]; ps += v * v; }
    psum[ty][tx] = ps;
    #pragma unroll
    for (int r = 0; r < 4; ++r){
        int t = t0 + ty + r*8;
        int c = c0 + tx;
        if (t < T_) embT[((size_t)b*T_ + t)*C_ + c] = f2bf(tile[tx][ty + r*8]);
    }
    __syncthreads();
    if (ty == 0){
        int t = t0 + tx;
        if (t < T_){
            float s2 = 0.f;
            #pragma unroll
            for (int w = 0; w < 8; ++w) s2 += psum[w][tx];
            atomicAdd(&esq[b*T_ + t], s2);
        }
    }
}

// ---------------- bf16 MFMA GEMM -> fp16 dot matrix (r2-proven 2-barrier 128^2) ----------------
__global__ __launch_bounds__(256) void gemm_dot_kernel(
    const unsigned short* __restrict__ A, const unsigned short* __restrict__ Bm,
    unsigned short* __restrict__ doth, int row_lo, int row_hi)
{
    __shared__ unsigned short smem[128*136];   // 34816 B; staging (16 KB) aliased in front
    unsigned short* As = smem;                 // 128*32
    unsigned short* Bs = smem + 128*32;        // 128*32
    int tid = threadIdx.x, lane = tid & 63, wv = tid >> 6;
    int row0 = row_lo + blockIdx.x * 128;
    int col0 = blockIdx.y * 128;

    int sr = lane >> 2;
    int sk = (lane & 3) * 8;
    int ar0 = row0 + wv*32 + sr;       int ar1 = ar0 + 16;
    int ca0 = (ar0 < N_) ? ar0 : N_-1; int ca1 = (ar1 < N_) ? ar1 : N_-1;
    const unsigned short* Ap0 = A  + (size_t)ca0 * C_ + sk;
    const unsigned short* Ap1 = A  + (size_t)ca1 * C_ + sk;
    const unsigned short* Bp0 = Bm + (size_t)(col0 + wv*32 + sr) * C_ + sk;
    const unsigned short* Bp1 = Bp0 + (size_t)16 * C_;
    unsigned short* Ad0 = &As[(wv*32     ) * 32];
    unsigned short* Ad1 = &As[(wv*32 + 16) * 32];
    unsigned short* Bd0 = &Bs[(wv*32     ) * 32];
    unsigned short* Bd1 = &Bs[(wv*32 + 16) * 32];

    int wm = (wv >> 1) * 64, wn = (wv & 1) * 64;
    int fr = lane & 15;
    int fk = (lane >> 4) * 8;

    f32x4 acc[4][4];
    #pragma unroll
    for (int i = 0; i < 4; ++i)
        #pragma unroll
        for (int j = 0; j < 4; ++j) acc[i][j] = (f32x4){0.f, 0.f, 0.f, 0.f};

    for (int kt = 0; kt < C_/32; ++kt){
        int k0 = kt * 32;
        gll16(Ap0 + k0, Ad0);
        gll16(Ap1 + k0, Ad1);
        gll16(Bp0 + k0, Bd0);
        gll16(Bp1 + k0, Bd1);
        __syncthreads();
        short8 af[4], bf[4];
        #pragma unroll
        for (int i = 0; i < 4; ++i) af[i] = *(const short8*)&As[(wm + i*16 + fr)*32 + fk];
        #pragma unroll
        for (int j = 0; j < 4; ++j) bf[j] = *(const short8*)&Bs[(wn + j*16 + fr)*32 + fk];
        #pragma unroll
        for (int i = 0; i < 4; ++i)
            #pragma unroll
            for (int j = 0; j < 4; ++j)
                acc[i][j] = __builtin_amdgcn_mfma_f32_16x16x32_bf16(bf[j], af[i], acc[i][j], 0, 0, 0);
        __syncthreads();
    }
    // loop ends with a barrier: safe to alias smem for the out-tile.

    // ---- stage 1: pack fp16 into LDS out-tile [128][136] ----
    const int LD = 136;
    int en = lane & 15;
    int ev = (lane >> 4) * 4;
    #pragma unroll
    for (int i = 0; i < 4; ++i){
        int r = wm + i*16 + en;
        #pragma unroll
        for (int j = 0; j < 4; ++j){
            ushort4 h;
            h.x = f2h(acc[i][j][0]);
            h.y = f2h(acc[i][j][1]);
            h.z = f2h(acc[i][j][2]);
            h.w = f2h(acc[i][j][3]);
            *(ushort4*)&smem[r*LD + wn + j*16 + ev] = h;
        }
    }
    __syncthreads();

    // ---- stage 2: coalesced stores, 16 lanes cover one row's 256B ----
    int rr = tid >> 4;          // 0..15
    int cc = (tid & 15) * 8;    // element col, 16B per lane
    #pragma unroll
    for (int it = 0; it < 8; ++it){
        int r = it*16 + rr;
        int n = row0 + r;
        if (n < row_hi){
            u16x8 v = *(const u16x8*)&smem[r*LD + cc];
            *(u16x8*)&doth[(size_t)(n - row_lo) * V_ + col0 + cc] = v;
        }
    }
}

// ---------------- selection v4.3: 1 wave/block, NO VGPR cap (launch_bounds(64) only) ----------------
// r10's body unchanged; only the launch bound's min-waves arg is dropped. r10's
// __launch_bounds__(64,4) capped VGPR at 64 -> u[64] spilled (WRITE_SIZE 66 MB).
// Without the cap the compiler allocates ~84-96 VGPRs; occupancy is then
// VGPR-bound at ~5 waves/SIMD -- the latency hiding r10 demonstrated (28->39%)
// without the spill that poisoned it.
__global__ __launch_bounds__(64) void select_kernel(const unsigned short* __restrict__ doth,
                                                    const int* __restrict__ codes,
                                                    const float* __restrict__ esq,
                                                    const float* __restrict__ csq,
                                                    float2* __restrict__ pairbuf,
                                                    int row_lo, int nrows){
    int lane = threadIdx.x;
    int lrow = blockIdx.x;
    if (lrow >= nrows) return;
    int n = row_lo + lrow;
    const u16x8* r8 = (const u16x8*)(doth + (size_t)lrow * V_);

    __shared__ unsigned hist[256] __attribute__((aligned(16)));
    __shared__ unsigned coll[64];
    __shared__ unsigned collcnt;

    float esq_n = esq[n];
    int code = codes[n];
    float dotc = h2f(doth[(size_t)lrow * V_ + code]);
    unsigned ucode = __float_as_uint(fmaxf(esq_n + csq[code] - 2.f * dotc, 0.f));

    // ---- load + reconstruct d2 bits, fused min/argmin/max in two half-chains ----
    unsigned u[64];
    unsigned mnA = 0xFFFFFFFFu, mxA = 0u, mnB = 0xFFFFFFFFu, mxB = 0u;
    int kmA = 0, kmB = 32;
    #pragma unroll
    for (int j = 0; j < 8; ++j){
        u16x8 h = r8[lane + j*64];
        const float4* cp = (const float4*)(csq + 8*lane + 512*j);
        float4 c0 = cp[0], c1 = cp[1];
        float cs[8] = {c0.x, c0.y, c0.z, c0.w, c1.x, c1.y, c1.z, c1.w};
        #pragma unroll
        for (int e = 0; e < 8; ++e){
            int k = 8*j + e;
            unsigned v = __float_as_uint(fmaxf(esq_n + cs[e] - 2.f * h2f(h[e]), 0.f));
            u[k] = v;
            if (j < 4){
                if (v < mnA){ mnA = v; kmA = k; }
                mxA = (v > mxA) ? v : mxA;
            } else {
                if (v < mnB){ mnB = v; kmB = k; }
                mxB = (v > mxB) ? v : mxB;
            }
        }
    }
    // merge halves: half A's global indices are all < half B's (idx grows with j),
    // so on equal values half A wins -> strict < for B.
    unsigned vmn = mnA; int km = kmA;
    if (mnB < mnA){ vmn = mnB; km = kmB; }
    unsigned vmx = (mxA > mxB) ? mxA : mxB;

    unsigned im = 8u*(unsigned)lane + (unsigned)(512*(km >> 3) + (km & 7));
    #pragma unroll
    for (int o = 32; o; o >>= 1){
        unsigned v2 = (unsigned)__shfl_xor((int)vmn, o, 64);
        unsigned i2 = (unsigned)__shfl_xor((int)im,  o, 64);
        if (v2 < vmn || (v2 == vmn && i2 < im)){ vmn = v2; im = i2; }
        unsigned x2 = (unsigned)__shfl_xor((int)vmx, o, 64); if (x2 > vmx) vmx = x2;
    }
    unsigned umin = vmn, umax = vmx;
    int idx0 = (int)im;
    float d0 = sqrtf(__uint_as_float(umin));

    // ---- rank-99 threshold t via histogram + in-bin bitwise search ----
    unsigned t;
    if (umin == umax){
        t = umin;
    } else {
        ((uint4*)&hist[0])[lane] = (uint4){0u,0u,0u,0u};
        if (lane == 0) collcnt = 0u;
        asm volatile("s_waitcnt lgkmcnt(0)" ::: "memory");
        float fmn = __uint_as_float(umin), fmx = __uint_as_float(umax);
        float invw = 256.0f / (fmx - fmn);
        #pragma unroll
        for (int k = 0; k < 64; ++k){
            float fk = __uint_as_float(u[k]);
            int b = (int)((fk - fmn) * invw); b = (b > 255) ? 255 : b;
            atomicAdd(&hist[b], 1u);
        }
        asm volatile("s_waitcnt lgkmcnt(0)" ::: "memory");
        uint4 hq = ((uint4*)&hist[0])[lane];
        unsigned lsum = hq.x + hq.y + hq.z + hq.w;
        unsigned inc = lsum;
        #pragma unroll
        for (int o = 1; o < 64; o <<= 1){
            unsigned y = (unsigned)__shfl_up((int)inc, o, 64);
            if (lane >= o) inc += y;
        }
        unsigned e0 = inc - lsum;
        unsigned e1 = e0 + hq.x, e2 = e1 + hq.y, e3 = e2 + hq.z, e4 = e3 + hq.w;
        int sel = -1;
        if      (e0 <= 99u && 99u < e1) sel = 0;
        else if (e1 <= 99u && 99u < e2) sel = 1;
        else if (e2 <= 99u && 99u < e3) sel = 2;
        else if (e3 <= 99u && 99u < e4) sel = 3;
        u64 bal = __ballot(sel >= 0);
        int src = __ffsll(bal) - 1;
        unsigned myBk = (unsigned)(4*lane + (sel < 0 ? 0 : sel));
        unsigned myBase = (sel == 1) ? e1 : (sel == 2) ? e2 : (sel == 3) ? e3 : e0;
        int Bk   = __shfl((int)myBk,   src, 64);
        int base = __shfl((int)myBase, src, 64);
        int rk = 99 - base;
        #pragma unroll
        for (int k = 0; k < 64; ++k){
            float fk = __uint_as_float(u[k]);
            int b = (int)((fk - fmn) * invw); b = (b > 255) ? 255 : b;
            if (b == Bk){
                unsigned pos = atomicAdd(&collcnt, 1u);
                if (pos < 64u) coll[pos] = u[k];
            }
        }
        asm volatile("s_waitcnt lgkmcnt(0)" ::: "memory");
        unsigned bcnt = collcnt;
        if (bcnt <= 64u){
            unsigned w = (lane < (int)bcnt) ? coll[lane] : 0xFFFFFFFFu;
            unsigned wmn = (lane < (int)bcnt) ? w : 0xFFFFFFFFu;
            unsigned wmx = (lane < (int)bcnt) ? w : 0u;
            #pragma unroll
            for (int o = 32; o; o >>= 1){
                unsigned a = (unsigned)__shfl_xor((int)wmn, o, 64); if (a < wmn) wmn = a;
                unsigned b = (unsigned)__shfl_xor((int)wmx, o, 64); if (b > wmx) wmx = b;
            }
            unsigned P;
            if (wmn == wmx) P = wmn;
            else {
                int hb = 31 - __clz((int)(wmn ^ wmx));
                unsigned mask = (hb == 31) ? 0xFFFFFFFFu : ((1u << (hb+1)) - 1u);
                P = wmn & ~mask;
                for (int b = hb; b >= 0; --b){
                    unsigned cand = P | (1u << b);
                    int c = __popcll(__ballot(w < cand));
                    if (c <= rk) P = cand;
                }
            }
            t = P;
        } else {
            int hb = 31 - __clz((int)(umin ^ umax));
            unsigned mask = (hb == 31) ? 0xFFFFFFFFu : ((1u << (hb+1)) - 1u);
            unsigned P = umin & ~mask;
            for (int b = hb; b >= 0; --b){
                unsigned cand = P | (1u << b);
                int c = 0;
                #pragma unroll
                for (int k = 0; k < 64; ++k) c += (u[k] < cand) ? 1 : 0;
                #pragma unroll
                for (int o = 32; o; o >>= 1) c += __shfl_xor(c, o, 64);
                if (c <= 99) P = cand;
            }
            t = P;
        }
    }
    float tval = sqrtf(__uint_as_float(t));

    // ---- softmax denom over top-100: 4 independent accumulation chains ----
    float s0 = 0.f, s1 = 0.f, s2 = 0.f, s3 = 0.f;
    int c0i = 0, c1i = 0, c2i = 0, c3i = 0;
    #pragma unroll
    for (int k = 0; k < 64; k += 4){
        if (u[k  ] < t){ s0 += __expf(d0 - sqrtf(__uint_as_float(u[k  ]))); c0i++; }
        if (u[k+1] < t){ s1 += __expf(d0 - sqrtf(__uint_as_float(u[k+1]))); c1i++; }
        if (u[k+2] < t){ s2 += __expf(d0 - sqrtf(__uint_as_float(u[k+2]))); c2i++; }
        if (u[k+3] < t){ s3 += __expf(d0 - sqrtf(__uint_as_float(u[k+3]))); c3i++; }
    }
    float s = (s0 + s1) + (s2 + s3);
    int cl = (c0i + c1i) + (c2i + c3i);
    #pragma unroll
    for (int o = 32; o; o >>= 1){
        s += __shfl_xor(s, o, 64);
        cl += __shfl_xor(cl, o, 64);
    }
    if (lane == 0){
        float S = s + (float)(K_ - cl) * __expf(d0 - tval);
        float dcode = sqrtf(__uint_as_float(ucode));
        if (ucode > t) S += __expf(d0 - dcode) - __expf(d0 - tval);  // include_correct swap
        float nll = dcode - d0 + __logf(S);
        pairbuf[n] = make_float2(nll, (idx0 == code) ? 1.f : 0.f);
    }
}

__global__ __launch_bounds__(1024) void finalize_kernel(const float2* __restrict__ pair,
                                                        float* __restrict__ out){
    int tid = threadIdx.x;
    float sn = 0.f, sh = 0.f;
    for (int i = tid; i < N_; i += 1024){
        float2 p = pair[i]; sn += p.x; sh += p.y;
    }
    #pragma unroll
    for (int o = 32; o; o >>= 1){ sn += __shfl_down(sn, o, 64); sh += __shfl_down(sh, o, 64); }
    __shared__ float a[16], b[16];
    int wv = tid >> 6, lane = tid & 63;
    if (lane == 0){ a[wv] = sn; b[wv] = sh; }
    __syncthreads();
    if (tid == 0){
        float L = 0.f, H = 0.f;
        #pragma unroll
        for (int i = 0; i < 16; ++i){ L += a[i]; H += b[i]; }
        out[0] = L / (float)N_;
        out[1] = H / (float)N_;   // local prediction is always candidate 0
        out[2] = H / (float)N_;
        out[3] = 1.0f;            // include_correct guarantees membership
    }
}

// ---------------- launcher (gemm split 2, single full-N select) ----------------
extern "C" void kernel_launch(void* const* d_in, const int* in_sizes, int n_in,
                              void* d_out, int out_size, void* d_ws, size_t ws_size,
                              hipStream_t stream){
    const float* S   = (const float*)d_in[0];
    const int* codes = (const int*)d_in[1];
    const float* CB  = (const float*)d_in[2];
    float* out = (float*)d_out;

    char* w = (char*)d_ws;
    size_t off = 0;
    unsigned short* embT = (unsigned short*)(w + off); off += (size_t)NPAD_ * C_ * 2;
    unsigned short* CBh  = (unsigned short*)(w + off); off += (size_t)V_ * C_ * 2;
    float* csq = (float*)(w + off); off += (size_t)V_ * 4;
    float* esq = (float*)(w + off); off += (size_t)N_ * 4;
    off = (off + 255) & ~(size_t)255;
    float2* pairbuf = (float2*)(w + off); off += (size_t)N_ * 8;
    unsigned short* dotbuf = (unsigned short*)(w + off);

    size_t avail = (ws_size > off) ? ws_size - off : 0;
    long maxrows = (long)(avail / ((size_t)V_ * 2));

    hipMemsetAsync(esq, 0, (size_t)N_ * 4, stream);
    hipLaunchKernelGGL(cbconv_kernel, dim3(V_/4), dim3(256), 0, stream, CB, CBh, csq);
    hipLaunchKernelGGL(transpose_conv_kernel, dim3((T_+31)/32, C_/32, B_), dim3(32, 8), 0, stream,
                       S, embT, esq);

    if (maxrows >= N_){
        const int gchunk = 6144;   // multiple of 128
        for (int row_lo = 0; row_lo < N_; row_lo += gchunk){
            int row_hi = row_lo + gchunk; if (row_hi > N_) row_hi = N_;
            int rows = row_hi - row_lo;
            hipLaunchKernelGGL(gemm_dot_kernel, dim3((rows + 127)/128, V_/128), dim3(256), 0, stream,
                               embT, CBh, dotbuf + (size_t)row_lo * V_, row_lo, row_hi);
        }
        hipLaunchKernelGGL(select_kernel, dim3(N_), dim3(64), 0, stream,
                           dotbuf, codes, esq, csq, pairbuf, 0, N_);
    } else {
        int chunk = (int)(maxrows & ~127L);
        if (chunk < 128) chunk = 128;
        for (int row_lo = 0; row_lo < N_; row_lo += chunk){
            int row_hi = row_lo + chunk; if (row_hi > N_) row_hi = N_;
            int rows = row_hi - row_lo;
            hipLaunchKernelGGL(gemm_dot_kernel, dim3((rows + 127)/128, V_/128), dim3(256), 0, stream,
                               embT, CBh, dotbuf, row_lo, row_hi);
            hipLaunchKernelGGL(select_kernel, dim3(rows), dim3(64), 0, stream,
                               dotbuf, codes, esq, csq, pairbuf, row_lo, rows);
        }
    }
    hipLaunchKernelGGL(finalize_kernel, dim3(1), dim3(1024), 0, stream, pairbuf, out);
}

// Round 12
// 213.965 us; speedup vs baseline: 1.0928x; 1.0138x over previous
//
#include <hip/hip_runtime.h>
#include <hip/hip_bf16.h>
#include <cstdint>

#define B_ 8
#define C_ 512
#define T_ 1500
#define N_ (B_*T_)      // 12000 tokens
#define NPAD_ 12032
#define V_ 4096
#define K_ 100
#define NCB_ 16         // C_/32 c-blocks -> esq partials

typedef unsigned long long u64;
typedef __attribute__((ext_vector_type(8))) short short8;
typedef __attribute__((ext_vector_type(8))) unsigned short u16x8;
typedef __attribute__((ext_vector_type(4))) float f32x4;

__device__ __forceinline__ unsigned short f2bf(float x){
    __hip_bfloat16 h = __float2bfloat16(x);
    return __builtin_bit_cast(unsigned short, h);
}
__device__ __forceinline__ unsigned short f2h(float x){
    return __builtin_bit_cast(unsigned short, (_Float16)x);
}
__device__ __forceinline__ float h2f(unsigned short h){
    return (float)__builtin_bit_cast(_Float16, h);
}

__device__ __forceinline__ void gll16(const unsigned short* g, unsigned short* l){
    __builtin_amdgcn_global_load_lds(
        (const __attribute__((address_space(1))) void*)g,
        (__attribute__((address_space(3))) void*)l, 16, 0, 0);
}

// ---------------- fused prep: codebook conv (blocks 0..1023) + student transpose ----------------
// cbconv: fp32 codebook -> bf16 + csq.  transpose: (B,C,T) fp32 -> embT bf16 (N,C) +
// per-c-block esq partials (plain stores, no atomics -> no memset dispatch needed).
__global__ __launch_bounds__(256) void prep_kernel(const float* __restrict__ CB,
                                                   unsigned short* __restrict__ CBh,
                                                   float* __restrict__ csq,
                                                   const float* __restrict__ S,
                                                   unsigned short* __restrict__ embT,
                                                   float* __restrict__ esqp){
    __shared__ float tile[32][33];
    __shared__ float psum[8][33];
    int bid = blockIdx.x;
    if (bid < V_/4){
        // ---- cbconv path ----
        int wv = threadIdx.x >> 6, lane = threadIdx.x & 63;
        int r = bid * 4 + wv;
        const float4* p4 = (const float4*)(CB + (size_t)r * C_);
        ushort4* o4 = (ushort4*)(CBh + (size_t)r * C_);
        float s = 0.f;
        #pragma unroll
        for (int j = 0; j < 2; ++j){
            float4 v = p4[lane + j*64];
            s += v.x*v.x + v.y*v.y + v.z*v.z + v.w*v.w;
            ushort4 h; h.x = f2bf(v.x); h.y = f2bf(v.y); h.z = f2bf(v.z); h.w = f2bf(v.w);
            o4[lane + j*64] = h;
        }
        #pragma unroll
        for (int o = 32; o; o >>= 1) s += __shfl_down(s, o, 64);
        if (lane == 0) csq[r] = s;
        return;
    }
    // ---- transpose path: remap flat block id to (t-block, c-block, batch) ----
    int idx = bid - V_/4;
    const int NTB = (T_ + 31) / 32;          // 47
    int bxt = idx % NTB;
    int byc = (idx / NTB) % NCB_;
    int bz  = idx / (NTB * NCB_);
    int c0 = byc * 32;
    int t0 = bxt * 32;
    int tx = threadIdx.x & 31, ty = threadIdx.x >> 5;  // 32 x 8
    #pragma unroll
    for (int r = 0; r < 4; ++r){
        int c = c0 + ty + r*8;
        int t = t0 + tx;
        tile[ty + r*8][tx] = (t < T_) ? S[((size_t)bz*C_ + c)*T_ + t] : 0.f;
    }
    __syncthreads();
    float ps = 0.f;
    #pragma unroll
    for (int r = 0; r < 4; ++r){ float v = tile[ty + r*8][tx]; ps += v * v; }
    psum[ty][tx] = ps;
    #pragma unroll
    for (int r = 0; r < 4; ++r){
        int t = t0 + ty + r*8;
        int c = c0 + tx;
        if (t < T_) embT[((size_t)bz*T_ + t)*C_ + c] = f2bf(tile[tx][ty + r*8]);
    }
    __syncthreads();
    if (ty == 0){
        int t = t0 + tx;
        if (t < T_){
            float s2 = 0.f;
            #pragma unroll
            for (int w = 0; w < 8; ++w) s2 += psum[w][tx];
            esqp[(size_t)byc * N_ + bz*T_ + t] = s2;   // plain store, no atomic
        }
    }
}

// ---------------- bf16 MFMA GEMM -> fp16 dot matrix (r2-proven 2-barrier 128^2) ----------------
__global__ __launch_bounds__(256) void gemm_dot_kernel(
    const unsigned short* __restrict__ A, const unsigned short* __restrict__ Bm,
    unsigned short* __restrict__ doth, int row_lo, int row_hi)
{
    __shared__ unsigned short smem[128*136];   // 34816 B; staging (16 KB) aliased in front
    unsigned short* As = smem;                 // 128*32
    unsigned short* Bs = smem + 128*32;        // 128*32
    int tid = threadIdx.x, lane = tid & 63, wv = tid >> 6;
    int row0 = row_lo + blockIdx.x * 128;
    int col0 = blockIdx.y * 128;

    int sr = lane >> 2;
    int sk = (lane & 3) * 8;
    int ar0 = row0 + wv*32 + sr;       int ar1 = ar0 + 16;
    int ca0 = (ar0 < N_) ? ar0 : N_-1; int ca1 = (ar1 < N_) ? ar1 : N_-1;
    const unsigned short* Ap0 = A  + (size_t)ca0 * C_ + sk;
    const unsigned short* Ap1 = A  + (size_t)ca1 * C_ + sk;
    const unsigned short* Bp0 = Bm + (size_t)(col0 + wv*32 + sr) * C_ + sk;
    const unsigned short* Bp1 = Bp0 + (size_t)16 * C_;
    unsigned short* Ad0 = &As[(wv*32     ) * 32];
    unsigned short* Ad1 = &As[(wv*32 + 16) * 32];
    unsigned short* Bd0 = &Bs[(wv*32     ) * 32];
    unsigned short* Bd1 = &Bs[(wv*32 + 16) * 32];

    int wm = (wv >> 1) * 64, wn = (wv & 1) * 64;
    int fr = lane & 15;
    int fk = (lane >> 4) * 8;

    f32x4 acc[4][4];
    #pragma unroll
    for (int i = 0; i < 4; ++i)
        #pragma unroll
        for (int j = 0; j < 4; ++j) acc[i][j] = (f32x4){0.f, 0.f, 0.f, 0.f};

    for (int kt = 0; kt < C_/32; ++kt){
        int k0 = kt * 32;
        gll16(Ap0 + k0, Ad0);
        gll16(Ap1 + k0, Ad1);
        gll16(Bp0 + k0, Bd0);
        gll16(Bp1 + k0, Bd1);
        __syncthreads();
        short8 af[4], bf[4];
        #pragma unroll
        for (int i = 0; i < 4; ++i) af[i] = *(const short8*)&As[(wm + i*16 + fr)*32 + fk];
        #pragma unroll
        for (int j = 0; j < 4; ++j) bf[j] = *(const short8*)&Bs[(wn + j*16 + fr)*32 + fk];
        #pragma unroll
        for (int i = 0; i < 4; ++i)
            #pragma unroll
            for (int j = 0; j < 4; ++j)
                acc[i][j] = __builtin_amdgcn_mfma_f32_16x16x32_bf16(bf[j], af[i], acc[i][j], 0, 0, 0);
        __syncthreads();
    }
    // loop ends with a barrier: safe to alias smem for the out-tile.

    // ---- stage 1: pack fp16 into LDS out-tile [128][136] ----
    const int LD = 136;
    int en = lane & 15;
    int ev = (lane >> 4) * 4;
    #pragma unroll
    for (int i = 0; i < 4; ++i){
        int r = wm + i*16 + en;
        #pragma unroll
        for (int j = 0; j < 4; ++j){
            ushort4 h;
            h.x = f2h(acc[i][j][0]);
            h.y = f2h(acc[i][j][1]);
            h.z = f2h(acc[i][j][2]);
            h.w = f2h(acc[i][j][3]);
            *(ushort4*)&smem[r*LD + wn + j*16 + ev] = h;
        }
    }
    __syncthreads();

    // ---- stage 2: coalesced stores, 16 lanes cover one row's 256B ----
    int rr = tid >> 4;          // 0..15
    int cc = (tid & 15) * 8;    // element col, 16B per lane
    #pragma unroll
    for (int it = 0; it < 8; ++it){
        int r = it*16 + rr;
        int n = row0 + r;
        if (n < row_hi){
            u16x8 v = *(const u16x8*)&smem[r*LD + cc];
            *(u16x8*)&doth[(size_t)(n - row_lo) * V_ + col0 + cc] = v;
        }
    }
}

// ---------------- selection v4.1 (r9-proven): esq from 16 partials ----------------
__global__ __launch_bounds__(256, 2) void select_kernel(const unsigned short* __restrict__ doth,
                                                        const int* __restrict__ codes,
                                                        const float* __restrict__ esqp,
                                                        const float* __restrict__ csq,
                                                        float2* __restrict__ pairbuf,
                                                        int row_lo, int nrows){
    int tid = threadIdx.x, lane = tid & 63, wv = tid >> 6;
    int lrow = blockIdx.x * 4 + wv;
    if (lrow >= nrows) return;               // wave-uniform, no barriers below
    int n = row_lo + lrow;
    const u16x8* r8 = (const u16x8*)(doth + (size_t)lrow * V_);

    __shared__ unsigned hist[4][256] __attribute__((aligned(16)));
    __shared__ unsigned coll[4][64];
    __shared__ unsigned collcnt[4];

    // esq from 16 per-c-block partials (wave-uniform scalar loads)
    float esq_n = 0.f;
    #pragma unroll
    for (int p = 0; p < NCB_; ++p) esq_n += esqp[(size_t)p * N_ + n];

    int code = codes[n];
    float dotc = h2f(doth[(size_t)lrow * V_ + code]);
    unsigned ucode = __float_as_uint(fmaxf(esq_n + csq[code] - 2.f * dotc, 0.f));

    // ---- load + reconstruct d2 bits, fused per-lane min/argmin/max ----
    unsigned u[64];
    unsigned vmn = 0xFFFFFFFFu, vmx = 0u;
    int km = 0;
    #pragma unroll
    for (int j = 0; j < 8; ++j){
        u16x8 h = r8[lane + j*64];
        const float4* cp = (const float4*)(csq + 8*lane + 512*j);
        float4 c0 = cp[0], c1 = cp[1];
        float cs[8] = {c0.x, c0.y, c0.z, c0.w, c1.x, c1.y, c1.z, c1.w};
        #pragma unroll
        for (int e = 0; e < 8; ++e){
            int k = 8*j + e;
            unsigned v = __float_as_uint(fmaxf(esq_n + cs[e] - 2.f * h2f(h[e]), 0.f));
            u[k] = v;
            if (v < vmn){ vmn = v; km = k; }
            vmx = (v > vmx) ? v : vmx;
        }
    }
    // joint (val, idx) lexicographic reduce + max reduce
    unsigned im = 8u*(unsigned)lane + (unsigned)(512*(km >> 3) + (km & 7));
    #pragma unroll
    for (int o = 32; o; o >>= 1){
        unsigned v2 = (unsigned)__shfl_xor((int)vmn, o, 64);
        unsigned i2 = (unsigned)__shfl_xor((int)im,  o, 64);
        if (v2 < vmn || (v2 == vmn && i2 < im)){ vmn = v2; im = i2; }
        unsigned x2 = (unsigned)__shfl_xor((int)vmx, o, 64); if (x2 > vmx) vmx = x2;
    }
    unsigned umin = vmn, umax = vmx;
    int idx0 = (int)im;
    float d0 = sqrtf(__uint_as_float(umin));

    // ---- rank-99 threshold t via per-wave histogram + in-bin bitwise search ----
    unsigned t;
    if (umin == umax){
        t = umin;
    } else {
        ((uint4*)&hist[wv][0])[lane] = (uint4){0u,0u,0u,0u};
        if (lane == 0) collcnt[wv] = 0u;
        asm volatile("s_waitcnt lgkmcnt(0)" ::: "memory");
        float fmn = __uint_as_float(umin), fmx = __uint_as_float(umax);
        float invw = 256.0f / (fmx - fmn);
        #pragma unroll
        for (int k = 0; k < 64; ++k){
            float fk = __uint_as_float(u[k]);
            int b = (int)((fk - fmn) * invw); b = (b > 255) ? 255 : b;
            atomicAdd(&hist[wv][b], 1u);
        }
        asm volatile("s_waitcnt lgkmcnt(0)" ::: "memory");
        uint4 hq = ((uint4*)&hist[wv][0])[lane];
        unsigned lsum = hq.x + hq.y + hq.z + hq.w;
        unsigned inc = lsum;
        #pragma unroll
        for (int o = 1; o < 64; o <<= 1){
            unsigned y = (unsigned)__shfl_up((int)inc, o, 64);
            if (lane >= o) inc += y;
        }
        unsigned e0 = inc - lsum;
        unsigned e1 = e0 + hq.x, e2 = e1 + hq.y, e3 = e2 + hq.z, e4 = e3 + hq.w;
        int sel = -1;
        if      (e0 <= 99u && 99u < e1) sel = 0;
        else if (e1 <= 99u && 99u < e2) sel = 1;
        else if (e2 <= 99u && 99u < e3) sel = 2;
        else if (e3 <= 99u && 99u < e4) sel = 3;
        u64 bal = __ballot(sel >= 0);
        int src = __ffsll(bal) - 1;
        unsigned myBk = (unsigned)(4*lane + (sel < 0 ? 0 : sel));
        unsigned myBase = (sel == 1) ? e1 : (sel == 2) ? e2 : (sel == 3) ? e3 : e0;
        int Bk   = __shfl((int)myBk,   src, 64);
        int base = __shfl((int)myBase, src, 64);
        int rk = 99 - base;
        #pragma unroll
        for (int k = 0; k < 64; ++k){
            float fk = __uint_as_float(u[k]);
            int b = (int)((fk - fmn) * invw); b = (b > 255) ? 255 : b;
            if (b == Bk){
                unsigned pos = atomicAdd(&collcnt[wv], 1u);
                if (pos < 64u) coll[wv][pos] = u[k];
            }
        }
        asm volatile("s_waitcnt lgkmcnt(0)" ::: "memory");
        unsigned bcnt = collcnt[wv];
        if (bcnt <= 64u){
            unsigned w = (lane < (int)bcnt) ? coll[wv][lane] : 0xFFFFFFFFu;
            unsigned wmn = (lane < (int)bcnt) ? w : 0xFFFFFFFFu;
            unsigned wmx = (lane < (int)bcnt) ? w : 0u;
            #pragma unroll
            for (int o = 32; o; o >>= 1){
                unsigned a = (unsigned)__shfl_xor((int)wmn, o, 64); if (a < wmn) wmn = a;
                unsigned b = (unsigned)__shfl_xor((int)wmx, o, 64); if (b > wmx) wmx = b;
            }
            unsigned P;
            if (wmn == wmx) P = wmn;
            else {
                int hb = 31 - __clz((int)(wmn ^ wmx));
                unsigned mask = (hb == 31) ? 0xFFFFFFFFu : ((1u << (hb+1)) - 1u);
                P = wmn & ~mask;
                for (int b = hb; b >= 0; --b){
                    unsigned cand = P | (1u << b);
                    int c = __popcll(__ballot(w < cand));
                    if (c <= rk) P = cand;
                }
            }
            t = P;
        } else {
            int hb = 31 - __clz((int)(umin ^ umax));
            unsigned mask = (hb == 31) ? 0xFFFFFFFFu : ((1u << (hb+1)) - 1u);
            unsigned P = umin & ~mask;
            for (int b = hb; b >= 0; --b){
                unsigned cand = P | (1u << b);
                int c = 0;
                #pragma unroll
                for (int k = 0; k < 64; ++k) c += (u[k] < cand) ? 1 : 0;
                #pragma unroll
                for (int o = 32; o; o >>= 1) c += __shfl_xor(c, o, 64);
                if (c <= 99) P = cand;
            }
            t = P;
        }
    }
    float tval = sqrtf(__uint_as_float(t));

    // ---- softmax denom over top-100 (tie multiplicity at t) ----
    float s = 0.f; int cl = 0;
    #pragma unroll
    for (int k = 0; k < 64; ++k){
        if (u[k] < t){ s += __expf(d0 - sqrtf(__uint_as_float(u[k]))); cl++; }
    }
    #pragma unroll
    for (int o = 32; o; o >>= 1){
        s += __shfl_xor(s, o, 64);
        cl += __shfl_xor(cl, o, 64);
    }
    if (lane == 0){
        float S = s + (float)(K_ - cl) * __expf(d0 - tval);
        float dcode = sqrtf(__uint_as_float(ucode));
        if (ucode > t) S += __expf(d0 - dcode) - __expf(d0 - tval);  // include_correct swap
        float nll = dcode - d0 + __logf(S);
        pairbuf[n] = make_float2(nll, (idx0 == code) ? 1.f : 0.f);
    }
}

__global__ __launch_bounds__(1024) void finalize_kernel(const float2* __restrict__ pair,
                                                        float* __restrict__ out){
    int tid = threadIdx.x;
    float sn = 0.f, sh = 0.f;
    for (int i = tid; i < N_; i += 1024){
        float2 p = pair[i]; sn += p.x; sh += p.y;
    }
    #pragma unroll
    for (int o = 32; o; o >>= 1){ sn += __shfl_down(sn, o, 64); sh += __shfl_down(sh, o, 64); }
    __shared__ float a[16], b[16];
    int wv = tid >> 6, lane = tid & 63;
    if (lane == 0){ a[wv] = sn; b[wv] = sh; }
    __syncthreads();
    if (tid == 0){
        float L = 0.f, H = 0.f;
        #pragma unroll
        for (int i = 0; i < 16; ++i){ L += a[i]; H += b[i]; }
        out[0] = L / (float)N_;
        out[1] = H / (float)N_;   // local prediction is always candidate 0
        out[2] = H / (float)N_;
        out[3] = 1.0f;            // include_correct guarantees membership
    }
}

// ---------------- launcher: 5 dispatches (prep, gemm x2, select, finalize) ----------------
extern "C" void kernel_launch(void* const* d_in, const int* in_sizes, int n_in,
                              void* d_out, int out_size, void* d_ws, size_t ws_size,
                              hipStream_t stream){
    const float* S   = (const float*)d_in[0];
    const int* codes = (const int*)d_in[1];
    const float* CB  = (const float*)d_in[2];
    float* out = (float*)d_out;

    char* w = (char*)d_ws;
    size_t off = 0;
    unsigned short* embT = (unsigned short*)(w + off); off += (size_t)NPAD_ * C_ * 2;
    unsigned short* CBh  = (unsigned short*)(w + off); off += (size_t)V_ * C_ * 2;
    float* csq  = (float*)(w + off); off += (size_t)V_ * 4;
    float* esqp = (float*)(w + off); off += (size_t)NCB_ * N_ * 4;
    off = (off + 255) & ~(size_t)255;
    float2* pairbuf = (float2*)(w + off); off += (size_t)N_ * 8;
    unsigned short* dotbuf = (unsigned short*)(w + off);

    size_t avail = (ws_size > off) ? ws_size - off : 0;
    long maxrows = (long)(avail / ((size_t)V_ * 2));

    const int NTB = (T_ + 31) / 32;
    int prep_blocks = V_/4 + NTB * NCB_ * B_;   // 1024 + 6016
    hipLaunchKernelGGL(prep_kernel, dim3(prep_blocks), dim3(256), 0, stream,
                       CB, CBh, csq, S, embT, esqp);

    if (maxrows >= N_){
        const int gchunk = 6144;   // multiple of 128
        for (int row_lo = 0; row_lo < N_; row_lo += gchunk){
            int row_hi = row_lo + gchunk; if (row_hi > N_) row_hi = N_;
            int rows = row_hi - row_lo;
            hipLaunchKernelGGL(gemm_dot_kernel, dim3((rows + 127)/128, V_/128), dim3(256), 0, stream,
                               embT, CBh, dotbuf + (size_t)row_lo * V_, row_lo, row_hi);
        }
        hipLaunchKernelGGL(select_kernel, dim3((N_ + 3)/4), dim3(256), 0, stream,
                           dotbuf, codes, esqp, csq, pairbuf, 0, N_);
    } else {
        int chunk = (int)(maxrows & ~127L);
        if (chunk < 128) chunk = 128;
        for (int row_lo = 0; row_lo < N_; row_lo += chunk){
            int row_hi = row_lo + chunk; if (row_hi > N_) row_hi = N_;
            int rows = row_hi - row_lo;
            hipLaunchKernelGGL(gemm_dot_kernel, dim3((rows + 127)/128, V_/128), dim3(256), 0, stream,
                               embT, CBh, dotbuf, row_lo, row_hi);
            hipLaunchKernelGGL(select_kernel, dim3((rows + 3)/4), dim3(256), 0, stream,
                               dotbuf, codes, esqp, csq, pairbuf, row_lo, rows);
        }
    }
    hipLaunchKernelGGL(finalize_kernel, dim3(1), dim3(1024), 0, stream, pairbuf, out);
}

// Round 13
// 209.392 us; speedup vs baseline: 1.1167x; 1.0218x over previous
//
#include <hip/hip_runtime.h>
#include <hip/hip_bf16.h>
#include <cstdint>

#define B_ 8
#define C_ 512
#define T_ 1500
#define N_ (B_*T_)      // 12000 tokens
#define NPAD_ 12032
#define V_ 4096
#define K_ 100
#define NCB_ 16         // C_/32 c-blocks -> esq partials

typedef unsigned long long u64;
typedef __attribute__((ext_vector_type(8))) short short8;
typedef __attribute__((ext_vector_type(8))) unsigned short u16x8;
typedef __attribute__((ext_vector_type(4))) float f32x4;

__device__ __forceinline__ unsigned short f2bf(float x){
    __hip_bfloat16 h = __float2bfloat16(x);
    return __builtin_bit_cast(unsigned short, h);
}
__device__ __forceinline__ unsigned short f2h(float x){
    return __builtin_bit_cast(unsigned short, (_Float16)x);
}
__device__ __forceinline__ float h2f(unsigned short h){
    return (float)__builtin_bit_cast(_Float16, h);
}

__device__ __forceinline__ void gll16(const unsigned short* g, unsigned short* l){
    __builtin_amdgcn_global_load_lds(
        (const __attribute__((address_space(1))) void*)g,
        (__attribute__((address_space(3))) void*)l, 16, 0, 0);
}

// ---------------- fused prep: codebook conv (blocks 0..1023) + student transpose ----------------
__global__ __launch_bounds__(256) void prep_kernel(const float* __restrict__ CB,
                                                   unsigned short* __restrict__ CBh,
                                                   float* __restrict__ csq,
                                                   const float* __restrict__ S,
                                                   unsigned short* __restrict__ embT,
                                                   float* __restrict__ esqp){
    __shared__ float tile[32][33];
    __shared__ float psum[8][33];
    int bid = blockIdx.x;
    if (bid < V_/4){
        // ---- cbconv path ----
        int wv = threadIdx.x >> 6, lane = threadIdx.x & 63;
        int r = bid * 4 + wv;
        const float4* p4 = (const float4*)(CB + (size_t)r * C_);
        ushort4* o4 = (ushort4*)(CBh + (size_t)r * C_);
        float s = 0.f;
        #pragma unroll
        for (int j = 0; j < 2; ++j){
            float4 v = p4[lane + j*64];
            s += v.x*v.x + v.y*v.y + v.z*v.z + v.w*v.w;
            ushort4 h; h.x = f2bf(v.x); h.y = f2bf(v.y); h.z = f2bf(v.z); h.w = f2bf(v.w);
            o4[lane + j*64] = h;
        }
        #pragma unroll
        for (int o = 32; o; o >>= 1) s += __shfl_down(s, o, 64);
        if (lane == 0) csq[r] = s;
        return;
    }
    // ---- transpose path ----
    int idx = bid - V_/4;
    const int NTB = (T_ + 31) / 32;          // 47
    int bxt = idx % NTB;
    int byc = (idx / NTB) % NCB_;
    int bz  = idx / (NTB * NCB_);
    int c0 = byc * 32;
    int t0 = bxt * 32;
    int tx = threadIdx.x & 31, ty = threadIdx.x >> 5;  // 32 x 8
    #pragma unroll
    for (int r = 0; r < 4; ++r){
        int c = c0 + ty + r*8;
        int t = t0 + tx;
        tile[ty + r*8][tx] = (t < T_) ? S[((size_t)bz*C_ + c)*T_ + t] : 0.f;
    }
    __syncthreads();
    float ps = 0.f;
    #pragma unroll
    for (int r = 0; r < 4; ++r){ float v = tile[ty + r*8][tx]; ps += v * v; }
    psum[ty][tx] = ps;
    #pragma unroll
    for (int r = 0; r < 4; ++r){
        int t = t0 + ty + r*8;
        int c = c0 + tx;
        if (t < T_) embT[((size_t)bz*T_ + t)*C_ + c] = f2bf(tile[tx][ty + r*8]);
    }
    __syncthreads();
    if (ty == 0){
        int t = t0 + tx;
        if (t < T_){
            float s2 = 0.f;
            #pragma unroll
            for (int w = 0; w < 8; ++w) s2 += psum[w][tx];
            esqp[(size_t)byc * N_ + bz*T_ + t] = s2;   // plain store, no atomic
        }
    }
}

// ---------------- bf16 MFMA GEMM -> fp16 dot matrix (r2-proven 2-barrier 128^2) ----------------
__global__ __launch_bounds__(256) void gemm_dot_kernel(
    const unsigned short* __restrict__ A, const unsigned short* __restrict__ Bm,
    unsigned short* __restrict__ doth, int row_lo, int row_hi)
{
    __shared__ unsigned short smem[128*136];   // 34816 B; staging (16 KB) aliased in front
    unsigned short* As = smem;                 // 128*32
    unsigned short* Bs = smem + 128*32;        // 128*32
    int tid = threadIdx.x, lane = tid & 63, wv = tid >> 6;
    int row0 = row_lo + blockIdx.x * 128;
    int col0 = blockIdx.y * 128;

    int sr = lane >> 2;
    int sk = (lane & 3) * 8;
    int ar0 = row0 + wv*32 + sr;       int ar1 = ar0 + 16;
    int ca0 = (ar0 < N_) ? ar0 : N_-1; int ca1 = (ar1 < N_) ? ar1 : N_-1;
    const unsigned short* Ap0 = A  + (size_t)ca0 * C_ + sk;
    const unsigned short* Ap1 = A  + (size_t)ca1 * C_ + sk;
    const unsigned short* Bp0 = Bm + (size_t)(col0 + wv*32 + sr) * C_ + sk;
    const unsigned short* Bp1 = Bp0 + (size_t)16 * C_;
    unsigned short* Ad0 = &As[(wv*32     ) * 32];
    unsigned short* Ad1 = &As[(wv*32 + 16) * 32];
    unsigned short* Bd0 = &Bs[(wv*32     ) * 32];
    unsigned short* Bd1 = &Bs[(wv*32 + 16) * 32];

    int wm = (wv >> 1) * 64, wn = (wv & 1) * 64;
    int fr = lane & 15;
    int fk = (lane >> 4) * 8;

    f32x4 acc[4][4];
    #pragma unroll
    for (int i = 0; i < 4; ++i)
        #pragma unroll
        for (int j = 0; j < 4; ++j) acc[i][j] = (f32x4){0.f, 0.f, 0.f, 0.f};

    for (int kt = 0; kt < C_/32; ++kt){
        int k0 = kt * 32;
        gll16(Ap0 + k0, Ad0);
        gll16(Ap1 + k0, Ad1);
        gll16(Bp0 + k0, Bd0);
        gll16(Bp1 + k0, Bd1);
        __syncthreads();
        short8 af[4], bf[4];
        #pragma unroll
        for (int i = 0; i < 4; ++i) af[i] = *(const short8*)&As[(wm + i*16 + fr)*32 + fk];
        #pragma unroll
        for (int j = 0; j < 4; ++j) bf[j] = *(const short8*)&Bs[(wn + j*16 + fr)*32 + fk];
        #pragma unroll
        for (int i = 0; i < 4; ++i)
            #pragma unroll
            for (int j = 0; j < 4; ++j)
                acc[i][j] = __builtin_amdgcn_mfma_f32_16x16x32_bf16(bf[j], af[i], acc[i][j], 0, 0, 0);
        __syncthreads();
    }
    // loop ends with a barrier: safe to alias smem for the out-tile.

    // ---- stage 1: pack fp16 into LDS out-tile [128][136] ----
    const int LD = 136;
    int en = lane & 15;
    int ev = (lane >> 4) * 4;
    #pragma unroll
    for (int i = 0; i < 4; ++i){
        int r = wm + i*16 + en;
        #pragma unroll
        for (int j = 0; j < 4; ++j){
            ushort4 h;
            h.x = f2h(acc[i][j][0]);
            h.y = f2h(acc[i][j][1]);
            h.z = f2h(acc[i][j][2]);
            h.w = f2h(acc[i][j][3]);
            *(ushort4*)&smem[r*LD + wn + j*16 + ev] = h;
        }
    }
    __syncthreads();

    // ---- stage 2: coalesced stores, 16 lanes cover one row's 256B ----
    int rr = tid >> 4;          // 0..15
    int cc = (tid & 15) * 8;    // element col, 16B per lane
    #pragma unroll
    for (int it = 0; it < 8; ++it){
        int r = it*16 + rr;
        int n = row0 + r;
        if (n < row_hi){
            u16x8 v = *(const u16x8*)&smem[r*LD + cc];
            *(u16x8*)&doth[(size_t)(n - row_lo) * V_ + col0 + cc] = v;
        }
    }
}

// ---------------- selection v5: 2 waves per ROW (halved serial chains, halved VGPR) ----------------
// Same algorithm/semantics as r12's v4.1; the row's 4096 values are split across
// 128 threads (32/thread, u[32] regs). Shared histogram (already atomic); scan and
// ballot searches computed redundantly per-wave on identical shared data (no
// broadcasts); ~5 two-wave barriers. Cross-wave merges via tiny LDS scratch.
__global__ __launch_bounds__(128) void select_kernel(const unsigned short* __restrict__ doth,
                                                     const int* __restrict__ codes,
                                                     const float* __restrict__ esqp,
                                                     const float* __restrict__ csq,
                                                     float2* __restrict__ pairbuf,
                                                     int row_lo, int nrows){
    int tid = threadIdx.x;              // 0..127
    int lane = tid & 63, wv = tid >> 6; // wave 0/1
    int lrow = blockIdx.x;
    if (lrow >= nrows) return;          // grid == nrows, never taken
    int n = row_lo + lrow;
    const u16x8* r8 = (const u16x8*)(doth + (size_t)lrow * V_);

    __shared__ unsigned hist[256] __attribute__((aligned(16)));
    __shared__ unsigned coll[64];
    __shared__ unsigned collcnt;
    __shared__ unsigned xmn[2], xim[2], xmx[2];
    __shared__ float xs[2];
    __shared__ int xcl[2];
    __shared__ int xc[2];

    // esq from 16 per-c-block partials (block-uniform scalar loads)
    float esq_n = 0.f;
    #pragma unroll
    for (int p = 0; p < NCB_; ++p) esq_n += esqp[(size_t)p * N_ + n];

    int code = codes[n];
    float dotc = h2f(doth[(size_t)lrow * V_ + code]);
    unsigned ucode = __float_as_uint(fmaxf(esq_n + csq[code] - 2.f * dotc, 0.f));

    // zero shared state early; first barrier (after min/max merge) publishes it
    ((uint2*)hist)[tid] = (uint2){0u, 0u};
    if (tid == 0) collcnt = 0u;

    // ---- reconstruct: thread covers chunks tid + j*128 (col = 8*tid + 1024*j + e) ----
    unsigned u[32];
    unsigned vmn = 0xFFFFFFFFu, vmx = 0u;
    int km = 0;
    #pragma unroll
    for (int j = 0; j < 4; ++j){
        u16x8 h = r8[tid + j*128];
        const float4* cp = (const float4*)(csq + 8*tid + 1024*j);
        float4 c0 = cp[0], c1 = cp[1];
        float cs[8] = {c0.x, c0.y, c0.z, c0.w, c1.x, c1.y, c1.z, c1.w};
        #pragma unroll
        for (int e = 0; e < 8; ++e){
            int k = 8*j + e;
            unsigned v = __float_as_uint(fmaxf(esq_n + cs[e] - 2.f * h2f(h[e]), 0.f));
            u[k] = v;
            if (v < vmn){ vmn = v; km = k; }   // idx strictly increases with k -> first min = lowest idx
            vmx = (v > vmx) ? v : vmx;
        }
    }
    // per-thread min's global col index
    unsigned im = 8u*(unsigned)tid + (unsigned)(1024*(km >> 3) + (km & 7));
    // wave-level joint (val,idx) + max reduce
    #pragma unroll
    for (int o = 32; o; o >>= 1){
        unsigned v2 = (unsigned)__shfl_xor((int)vmn, o, 64);
        unsigned i2 = (unsigned)__shfl_xor((int)im,  o, 64);
        if (v2 < vmn || (v2 == vmn && i2 < im)){ vmn = v2; im = i2; }
        unsigned x2 = (unsigned)__shfl_xor((int)vmx, o, 64); if (x2 > vmx) vmx = x2;
    }
    if (lane == 0){ xmn[wv] = vmn; xim[wv] = im; xmx[wv] = vmx; }
    __syncthreads();
    unsigned umin, umax; int idx0;
    {
        unsigned a0 = xmn[0], a1 = xmn[1], i0 = xim[0], i1 = xim[1];
        if (a1 < a0 || (a1 == a0 && i1 < i0)){ umin = a1; idx0 = (int)i1; }
        else                                 { umin = a0; idx0 = (int)i0; }
        umax = (xmx[0] > xmx[1]) ? xmx[0] : xmx[1];
    }
    float d0 = sqrtf(__uint_as_float(umin));

    // ---- rank-99 threshold t ----
    unsigned t;
    if (umin == umax){
        t = umin;                      // block-uniform branch
    } else {
        float fmn = __uint_as_float(umin), fmx = __uint_as_float(umax);
        float invw = 256.0f / (fmx - fmn);
        #pragma unroll
        for (int k = 0; k < 32; ++k){
            float fk = __uint_as_float(u[k]);
            int b = (int)((fk - fmn) * invw); b = (b > 255) ? 255 : b;
            atomicAdd(&hist[b], 1u);
        }
        __syncthreads();
        // both waves redundantly scan the shared histogram (identical results)
        uint4 hq = ((uint4*)hist)[lane];
        unsigned lsum = hq.x + hq.y + hq.z + hq.w;
        unsigned inc = lsum;
        #pragma unroll
        for (int o = 1; o < 64; o <<= 1){
            unsigned y = (unsigned)__shfl_up((int)inc, o, 64);
            if (lane >= o) inc += y;
        }
        unsigned e0 = inc - lsum;
        unsigned e1 = e0 + hq.x, e2 = e1 + hq.y, e3 = e2 + hq.z, e4 = e3 + hq.w;
        int sel = -1;
        if      (e0 <= 99u && 99u < e1) sel = 0;
        else if (e1 <= 99u && 99u < e2) sel = 1;
        else if (e2 <= 99u && 99u < e3) sel = 2;
        else if (e3 <= 99u && 99u < e4) sel = 3;
        u64 bal = __ballot(sel >= 0);
        int src = __ffsll(bal) - 1;
        unsigned myBk = (unsigned)(4*lane + (sel < 0 ? 0 : sel));
        unsigned myBase = (sel == 1) ? e1 : (sel == 2) ? e2 : (sel == 3) ? e3 : e0;
        int Bk   = __shfl((int)myBk,   src, 64);
        int base = __shfl((int)myBase, src, 64);
        int rk = 99 - base;
        // collect rank-bin values from both waves into shared coll
        #pragma unroll
        for (int k = 0; k < 32; ++k){
            float fk = __uint_as_float(u[k]);
            int b = (int)((fk - fmn) * invw); b = (b > 255) ? 255 : b;
            if (b == Bk){
                unsigned pos = atomicAdd(&collcnt, 1u);
                if (pos < 64u) coll[pos] = u[k];
            }
        }
        __syncthreads();
        int bcnt = (int)collcnt;       // block-uniform
        if (bcnt <= 64){
            unsigned w = (lane < bcnt) ? coll[lane] : 0xFFFFFFFFu;
            unsigned wmn = (lane < bcnt) ? w : 0xFFFFFFFFu;
            unsigned wmx = (lane < bcnt) ? w : 0u;
            #pragma unroll
            for (int o = 32; o; o >>= 1){
                unsigned a = (unsigned)__shfl_xor((int)wmn, o, 64); if (a < wmn) wmn = a;
                unsigned b = (unsigned)__shfl_xor((int)wmx, o, 64); if (b > wmx) wmx = b;
            }
            unsigned P;
            if (wmn == wmx) P = wmn;
            else {
                int hb = 31 - __clz((int)(wmn ^ wmx));
                unsigned mask = (hb == 31) ? 0xFFFFFFFFu : ((1u << (hb+1)) - 1u);
                P = wmn & ~mask;
                for (int b = hb; b >= 0; --b){
                    unsigned cand = P | (1u << b);
                    int c = __popcll(__ballot(w < cand));   // per-wave, identical in both
                    if (c <= rk) P = cand;
                }
            }
            t = P;
        } else {
            // rare fallback: cross-wave counting bitwise search
            int hb = 31 - __clz((int)(umin ^ umax));
            unsigned mask = (hb == 31) ? 0xFFFFFFFFu : ((1u << (hb+1)) - 1u);
            unsigned P = umin & ~mask;
            for (int b = hb; b >= 0; --b){
                unsigned cand = P | (1u << b);
                int c = 0;
                #pragma unroll
                for (int k = 0; k < 32; ++k) c += (u[k] < cand) ? 1 : 0;
                #pragma unroll
                for (int o = 32; o; o >>= 1) c += __shfl_xor(c, o, 64);
                if (lane == 0) xc[wv] = c;
                __syncthreads();
                int ctot = xc[0] + xc[1];
                __syncthreads();
                if (ctot <= 99) P = cand;
            }
            t = P;
        }
    }
    float tval = sqrtf(__uint_as_float(t));

    // ---- softmax denom over top-100 ----
    float s = 0.f; int cl = 0;
    #pragma unroll
    for (int k = 0; k < 32; ++k){
        if (u[k] < t){ s += __expf(d0 - sqrtf(__uint_as_float(u[k]))); cl++; }
    }
    #pragma unroll
    for (int o = 32; o; o >>= 1){
        s += __shfl_xor(s, o, 64);
        cl += __shfl_xor(cl, o, 64);
    }
    if (lane == 0){ xs[wv] = s; xcl[wv] = cl; }
    __syncthreads();
    if (tid == 0){
        float S = (xs[0] + xs[1]) + (float)(K_ - (xcl[0] + xcl[1])) * __expf(d0 - tval);
        float dcode = sqrtf(__uint_as_float(ucode));
        if (ucode > t) S += __expf(d0 - dcode) - __expf(d0 - tval);  // include_correct swap
        float nll = dcode - d0 + __logf(S);
        pairbuf[n] = make_float2(nll, (idx0 == code) ? 1.f : 0.f);
    }
}

__global__ __launch_bounds__(1024) void finalize_kernel(const float2* __restrict__ pair,
                                                        float* __restrict__ out){
    int tid = threadIdx.x;
    float sn = 0.f, sh = 0.f;
    for (int i = tid; i < N_; i += 1024){
        float2 p = pair[i]; sn += p.x; sh += p.y;
    }
    #pragma unroll
    for (int o = 32; o; o >>= 1){ sn += __shfl_down(sn, o, 64); sh += __shfl_down(sh, o, 64); }
    __shared__ float a[16], b[16];
    int wv = tid >> 6, lane = tid & 63;
    if (lane == 0){ a[wv] = sn; b[wv] = sh; }
    __syncthreads();
    if (tid == 0){
        float L = 0.f, H = 0.f;
        #pragma unroll
        for (int i = 0; i < 16; ++i){ L += a[i]; H += b[i]; }
        out[0] = L / (float)N_;
        out[1] = H / (float)N_;   // local prediction is always candidate 0
        out[2] = H / (float)N_;
        out[3] = 1.0f;            // include_correct guarantees membership
    }
}

// ---------------- launcher: 5 dispatches (prep, gemm x2, select, finalize) ----------------
extern "C" void kernel_launch(void* const* d_in, const int* in_sizes, int n_in,
                              void* d_out, int out_size, void* d_ws, size_t ws_size,
                              hipStream_t stream){
    const float* S   = (const float*)d_in[0];
    const int* codes = (const int*)d_in[1];
    const float* CB  = (const float*)d_in[2];
    float* out = (float*)d_out;

    char* w = (char*)d_ws;
    size_t off = 0;
    unsigned short* embT = (unsigned short*)(w + off); off += (size_t)NPAD_ * C_ * 2;
    unsigned short* CBh  = (unsigned short*)(w + off); off += (size_t)V_ * C_ * 2;
    float* csq  = (float*)(w + off); off += (size_t)V_ * 4;
    float* esqp = (float*)(w + off); off += (size_t)NCB_ * N_ * 4;
    off = (off + 255) & ~(size_t)255;
    float2* pairbuf = (float2*)(w + off); off += (size_t)N_ * 8;
    unsigned short* dotbuf = (unsigned short*)(w + off);

    size_t avail = (ws_size > off) ? ws_size - off : 0;
    long maxrows = (long)(avail / ((size_t)V_ * 2));

    const int NTB = (T_ + 31) / 32;
    int prep_blocks = V_/4 + NTB * NCB_ * B_;   // 1024 + 6016
    hipLaunchKernelGGL(prep_kernel, dim3(prep_blocks), dim3(256), 0, stream,
                       CB, CBh, csq, S, embT, esqp);

    if (maxrows >= N_){
        const int gchunk = 6144;   // multiple of 128
        for (int row_lo = 0; row_lo < N_; row_lo += gchunk){
            int row_hi = row_lo + gchunk; if (row_hi > N_) row_hi = N_;
            int rows = row_hi - row_lo;
            hipLaunchKernelGGL(gemm_dot_kernel, dim3((rows + 127)/128, V_/128), dim3(256), 0, stream,
                               embT, CBh, dotbuf + (size_t)row_lo * V_, row_lo, row_hi);
        }
        hipLaunchKernelGGL(select_kernel, dim3(N_), dim3(128), 0, stream,
                           dotbuf, codes, esqp, csq, pairbuf, 0, N_);
    } else {
        int chunk = (int)(maxrows & ~127L);
        if (chunk < 128) chunk = 128;
        for (int row_lo = 0; row_lo < N_; row_lo += chunk){
            int row_hi = row_lo + chunk; if (row_hi > N_) row_hi = N_;
            int rows = row_hi - row_lo;
            hipLaunchKernelGGL(gemm_dot_kernel, dim3((rows + 127)/128, V_/128), dim3(256), 0, stream,
                               embT, CBh, dotbuf, row_lo, row_hi);
            hipLaunchKernelGGL(select_kernel, dim3(rows), dim3(128), 0, stream,
                               dotbuf, codes, esqp, csq, pairbuf, row_lo, rows);
        }
    }
    hipLaunchKernelGGL(finalize_kernel, dim3(1), dim3(1024), 0, stream, pairbuf, out);
}